// Round 3
// baseline (368.817 us; speedup 1.0000x reference)
//
#include <hip/hip_runtime.h>
#include <math.h>

// Problem constants
#define N    130
#define NN   (130*130)       // 16900
#define NNN  (130*130*130)   // 2197000
#define NQ4  (NNN/4)         // 549250
#define NCH  12
#define XN   128
#define XNN  (XN*XN)

// Fused-kernel tiling
#define WT   5               // w tiles (32 lanes each, last partially valid)
#define HT   11              // h tiles (12 output rows each, 16 W rows computed)
#define DSEGS 9              // d segments, balanced: grid = 5*11*9 = 495 <= 512
                             // co-resident blocks (2/CU at <=128 VGPR)

typedef float f32x4 __attribute__((ext_vector_type(4)));

// ---------------------------------------------------------------------------
// Fused kernel: conv-diff^2 + 5x5x5 replicated box + channel min/mean.
//
// 12 channels = 12 orthogonal pairs of 6 shared neighbour values
//   Y0=d-, Y1=d+, Y2=h-, Y3=h+, Y4=w-, Y5=w+   (dilation-2 face neighbours)
// Per-dim addressing in box coords c in [0,129] (verified vs SH tables):
//   class  1 (center): ix = clamp(c-1,0,127), always valid
//   class -1:          ix = clamp(c-3,0,127), masked iff c==0
//   class  3:          ix = clamp(c+1,0,127), masked iff c==129
// Pairs: 0:(Y4,Y0) 1:(Y2,Y0) 2:(Y2,Y4) 3:(Y5,Y0) 4:(Y5,Y2) 5:(Y1,Y4)
//        6:(Y1,Y2) 7:(Y1,Y5) 8:(Y3,Y0) 9:(Y3,Y4) 10:(Y3,Y5) 11:(Y3,Y1)
//
// R3 changes vs R2:
//  - raw s_barrier (lgkmcnt-only wait) per step: global loads AND the 12
//    per-thread stores are no longer drained at every plane barrier
//    (__syncthreads emits s_waitcnt vmcnt(0) which serialized every step).
//  - the 5 cold-plane (Y1 / d+) loads are prefetched one step ahead; pc/pm
//    planes were touched 2 steps earlier and hit L1.
// ---------------------------------------------------------------------------
__global__ __launch_bounds__(512, 4) void k_fused(const float* __restrict__ x,
                                                  float* __restrict__ Cout,
                                                  double* __restrict__ acc) {
    const int tid = threadIdx.x;
    const int wl  = tid & 31;
    const int r   = tid >> 5;

    const int b    = blockIdx.x;
    const int wt   = b % WT;
    const int rest = b / WT;
    const int ht   = rest % HT;
    const int ds   = rest / HT;

    const int W0 = wt * 32;
    const int H0 = ht * 12;
    const int D0 = (ds * 130) / DSEGS;          // balanced d split
    const int D1 = ((ds + 1) * 130) / DSEGS;
    const int steps = (D1 - D0) + 4;            // 18 or 19

    const int  w_out = W0 + wl;
    const int  wc    = min(w_out, 129);                 // clamp garbage lanes
    const int  ghW   = min(max(H0 - 2 + r, 0), 129);    // W row (replicated)
    const int  oh    = H0 + r - 2;                      // output row (interior)
    const bool interior = (r >= 2) && (r < 14);
    const bool valid    = interior && (oh < N) && (w_out < N);

    // h-dim precompute (thread-invariant)
    const int   ih_c = min(max(ghW - 1, 0), 127);
    const int   ih_m = min(max(ghW - 3, 0), 127);
    const int   ih_p = min(ghW + 1, 127);
    const float fhm  = (ghW >= 1)   ? 1.0f : 0.0f;
    const float fhp  = (ghW <= 128) ? 1.0f : 0.0f;
    const int   dhm  = (ih_m - ih_c) * XN;
    const int   dhp  = (ih_p - ih_c) * XN;

    // w-dim per-tap precompute (thread-invariant)
    int   oc[5], o4[5], o5[5];
    float fwm[5], fwp[5];
    #pragma unroll
    for (int j = 0; j < 5; ++j) {
        const int cw = min(max(wc + j - 2, 0), 129);
        oc[j] = ih_c * XN + min(max(cw - 1, 0), 127);
        o4[j] = ih_c * XN + min(max(cw - 3, 0), 127);
        o5[j] = ih_c * XN + min(cw + 1, 127);
        fwm[j] = (cw >= 1)   ? 1.0f : 0.0f;
        fwp[j] = (cw <= 128) ? 1.0f : 0.0f;
    }

    __shared__ f32x4 Wlds[2][3][16][32];   // double-buffered plane, 48 KB
    __shared__ float red[512];

    f32x4 ring[5][3];                   // 5-deep d ring, 12 ch as 3x f32x4
    float lsum   = 0.0f;
    int   voxoff = D0 * NN + oh * N + w_out;   // element offset of next output

    // cold-plane (Y1 = d+) prefetch state
    float PF[5];
    float fdpP;

#define PRE(IT) do {                                                          \
    const int bdn = D0 - 2 + (IT);                                            \
    const int dcn = min(max(bdn, 0), 129);                                    \
    const float* ppn = x + (size_t)(min(dcn + 1, 127)) * XNN;                 \
    fdpP = (dcn <= 128) ? 1.0f : 0.0f;                                        \
    _Pragma("unroll") for (int j = 0; j < 5; ++j) PF[j] = ppn[oc[j]];         \
} while (0)

#define STEP(IT, SLOT, DOUT) do {                                             \
    const int it_ = (IT);                                                     \
    const int bd = D0 - 2 + it_;                                              \
    const int dc = min(max(bd, 0), 129);                                      \
    const float* pc = x + (size_t)(min(max(dc - 1, 0), 127)) * XNN;           \
    const float* pm = x + (size_t)(min(max(dc - 3, 0), 127)) * XNN;           \
    const float fdm = (dc >= 1)   ? 1.0f : 0.0f;                              \
    /* consume prefetched cold plane (loaded one step ago) */                 \
    const float fdp_ = fdpP;                                                  \
    float y1v[5];                                                             \
    _Pragma("unroll") for (int j = 0; j < 5; ++j) y1v[j] = PF[j] * fdp_;      \
    PRE(it_ + 1);                       /* issue next cold loads early */     \
    float Wa[12];                                                             \
    _Pragma("unroll") for (int z = 0; z < 12; ++z) Wa[z] = 0.0f;              \
    _Pragma("unroll") for (int j = 0; j < 5; ++j) {                           \
        const float y0 = pm[oc[j]]       * fdm;                               \
        const float y1 = y1v[j];                                              \
        const float y2 = pc[oc[j] + dhm] * fhm;                               \
        const float y3 = pc[oc[j] + dhp] * fhp;                               \
        const float y4 = pc[o4[j]]       * fwm[j];                            \
        const float y5 = pc[o5[j]]       * fwp[j];                            \
        float t;                                                              \
        t = y4 - y0; Wa[0]  += t * t;  t = y2 - y0; Wa[1]  += t * t;          \
        t = y2 - y4; Wa[2]  += t * t;  t = y5 - y0; Wa[3]  += t * t;          \
        t = y5 - y2; Wa[4]  += t * t;  t = y1 - y4; Wa[5]  += t * t;          \
        t = y1 - y2; Wa[6]  += t * t;  t = y1 - y5; Wa[7]  += t * t;          \
        t = y3 - y0; Wa[8]  += t * t;  t = y3 - y4; Wa[9]  += t * t;          \
        t = y3 - y5; Wa[10] += t * t;  t = y3 - y1; Wa[11] += t * t;          \
    }                                                                         \
    const int pb = it_ & 1;                                                   \
    Wlds[pb][0][r][wl] = (f32x4){Wa[0], Wa[1], Wa[2],  Wa[3]};                \
    Wlds[pb][1][r][wl] = (f32x4){Wa[4], Wa[5], Wa[6],  Wa[7]};                \
    Wlds[pb][2][r][wl] = (f32x4){Wa[8], Wa[9], Wa[10], Wa[11]};               \
    /* raw barrier: drain LDS writes only; global loads/stores stay live */   \
    __builtin_amdgcn_sched_barrier(0);                                        \
    asm volatile("s_waitcnt lgkmcnt(0)" ::: "memory");                        \
    __builtin_amdgcn_s_barrier();                                             \
    __builtin_amdgcn_sched_barrier(0);                                        \
    if (interior) {                                                           \
        _Pragma("unroll") for (int g = 0; g < 3; ++g) {                       \
            f32x4 a = Wlds[pb][g][r - 2][wl];                                 \
            a += Wlds[pb][g][r - 1][wl];                                      \
            a += Wlds[pb][g][r    ][wl];                                      \
            a += Wlds[pb][g][r + 1][wl];                                      \
            a += Wlds[pb][g][r + 2][wl];                                      \
            ring[SLOT][g] = a;                                                \
        }                                                                     \
        if (DOUT) {                                                           \
            f32x4 sg[3];                                                      \
            _Pragma("unroll") for (int g = 0; g < 3; ++g) {                   \
                f32x4 a = ring[0][g];                                         \
                a += ring[1][g]; a += ring[2][g];                             \
                a += ring[3][g]; a += ring[4][g];                             \
                sg[g] = a * (1.0f / 125.0f);                                  \
            }                                                                 \
            float sv[12];                                                     \
            _Pragma("unroll") for (int g = 0; g < 3; ++g) {                   \
                sv[4*g+0] = sg[g].x; sv[4*g+1] = sg[g].y;                     \
                sv[4*g+2] = sg[g].z; sv[4*g+3] = sg[g].w;                     \
            }                                                                 \
            float mn = sv[0], tt = sv[0];                                     \
            _Pragma("unroll") for (int z = 1; z < 12; ++z) {                  \
                mn = fminf(mn, sv[z]); tt += sv[z];                           \
            }                                                                 \
            if (valid) {                                                      \
                _Pragma("unroll") for (int z = 0; z < 12; ++z)                \
                    Cout[(size_t)z * NNN + (unsigned)voxoff] = sv[z] - mn;    \
                lsum += tt * (1.0f / 12.0f) - mn;     /* mind_var */          \
                voxoff += NN;                                                 \
            }                                                                 \
        }                                                                     \
    }                                                                         \
} while (0)

    PRE(0);
    // warmup: fill ring slots 0..3 (box planes D0-2 .. D0+1, clamped)
    STEP(0, 0, false);
    STEP(1, 1, false);
    STEP(2, 2, false);
    STEP(3, 3, false);

    // main: its 4..steps-1; base ≡ 4 (mod 5) keeps ring slots compile-time
    for (int base = 4; base < steps; base += 5) {
        STEP(base + 0, 4, true);
        if (base + 1 < steps) STEP(base + 1, 0, true);
        if (base + 2 < steps) STEP(base + 2, 1, true);
        if (base + 3 < steps) STEP(base + 3, 2, true);
        if (base + 4 < steps) STEP(base + 4, 3, true);
    }
#undef STEP
#undef PRE

    // block reduction of mind_var partial sum
    red[tid] = lsum;
    __syncthreads();
    for (int st = 256; st > 0; st >>= 1) {
        if (tid < st) red[tid] += red[tid + st];
        __syncthreads();
    }
    if (tid == 0) atomicAdd(acc, (double)red[0]);
}

// zero the accumulator
__global__ void k_zero(double* acc) {
    if (blockIdx.x == 0 && threadIdx.x == 0) *acc = 0.0;
}

// K3: in-place epilogue on d_out, float4-vectorized, fast exp.
// mvar = mean_ch(mind), clip to [1e-3,1e3]*mean, exp.
__global__ __launch_bounds__(256) void k_exp(float* __restrict__ io,
                                             const double* __restrict__ acc) {
    int q = blockIdx.x * 256 + threadIdx.x;      // float4 index
    if (q >= NQ4) return;
    const float mv_mean = (float)(*acc * (1.0 / (double)NNN));
    const float lo = mv_mean * 0.001f, hi = mv_mean * 1000.0f;

    f32x4 v[NCH];
    f32x4 tot = (f32x4){0.0f, 0.0f, 0.0f, 0.0f};
    #pragma unroll
    for (int o = 0; o < NCH; ++o) {
        v[o] = *((const f32x4*)io + (size_t)o * NQ4 + q);
        tot += v[o];
    }
    f32x4 inv;
    #pragma unroll
    for (int k = 0; k < 4; ++k) {
        float mvar = tot[k] * (1.0f / 12.0f);
        mvar = fminf(fmaxf(mvar, lo), hi);
        inv[k] = 1.0f / mvar;
    }
    #pragma unroll
    for (int o = 0; o < NCH; ++o) {
        f32x4 rr;
        #pragma unroll
        for (int k = 0; k < 4; ++k)
            rr[k] = __expf(-v[o][k] * inv[k]);
        *((f32x4*)io + (size_t)o * NQ4 + q) = rr;
    }
}

extern "C" void kernel_launch(void* const* d_in, const int* in_sizes, int n_in,
                              void* d_out, int out_size, void* d_ws, size_t ws_size,
                              hipStream_t stream) {
    const float* x = (const float*)d_in[0];
    float* out = (float*)d_out;                 // [12,130,130,130] f32
    double* acc = (double*)d_ws;

    k_zero <<<1, 64, 0, stream>>>(acc);
    k_fused<<<WT * HT * DSEGS, 512, 0, stream>>>(x, out, acc);   // 495 blocks
    k_exp  <<<(NQ4 + 255) / 256, 256, 0, stream>>>(out, acc);    // 2146 blocks
}

// Round 4
// 212.321 us; speedup vs baseline: 1.7371x; 1.7371x over previous
//
#include <hip/hip_runtime.h>
#include <math.h>

// Problem constants
#define N    130
#define NN   (130*130)       // 16900
#define NNN  (130*130*130)   // 2197000
#define NQ4  (NNN/4)         // 549250
#define NCH  12
#define XN   128
#define XNN  (XN*XN)

// Fused-kernel tiling
#define WT   5               // w tiles (32 lanes each, last partially valid)
#define HT   11              // h tiles (12 output rows each, 16 W rows computed)
#define DSEGS 9              // d segments, balanced: grid = 5*11*9 = 495 <= 512
                             // co-resident blocks (2/CU at <=128 VGPR)

typedef float f32x4 __attribute__((ext_vector_type(4)));

// ---------------------------------------------------------------------------
// Fused kernel: conv-diff^2 + 5x5x5 replicated box + channel min/mean.
//
// 12 channels = 12 orthogonal pairs of 6 shared neighbour values
//   Y0=d-, Y1=d+, Y2=h-, Y3=h+, Y4=w-, Y5=w+   (dilation-2 face neighbours)
// Per-dim addressing in box coords c in [0,129] (verified vs SH tables):
//   class  1 (center): ix = clamp(c-1,0,127), always valid
//   class -1:          ix = clamp(c-3,0,127), masked iff c==0
//   class  3:          ix = clamp(c+1,0,127), masked iff c==129
// Pairs: 0:(Y4,Y0) 1:(Y2,Y0) 2:(Y2,Y4) 3:(Y5,Y0) 4:(Y5,Y2) 5:(Y1,Y4)
//        6:(Y1,Y2) 7:(Y1,Y5) 8:(Y3,Y0) 9:(Y3,Y4) 10:(Y3,Y5) 11:(Y3,Y1)
//
// R4 changes vs R3 (de-confounding the R3 regression):
//  - plain __launch_bounds__(512): R3's (512,4) was interpreted as a
//    64-VGPR budget -> scratch spills -> 680 MB of spill traffic (FETCH
//    28->534 MB). Reverted.
//  - raw barrier KEPT (lgkmcnt-only wait; loads/stores stay in flight
//    across the per-plane barrier) but the sched_barrier(0) pins are
//    DROPPED: LDS ops are compiler-generated memory ops and cannot cross
//    the "memory"-clobbered asm, so ordering is already guaranteed and the
//    pins only constrained scheduling/regalloc.
// ---------------------------------------------------------------------------
__global__ __launch_bounds__(512) void k_fused(const float* __restrict__ x,
                                               float* __restrict__ Cout,
                                               double* __restrict__ acc) {
    const int tid = threadIdx.x;
    const int wl  = tid & 31;
    const int r   = tid >> 5;

    const int b    = blockIdx.x;
    const int wt   = b % WT;
    const int rest = b / WT;
    const int ht   = rest % HT;
    const int ds   = rest / HT;

    const int W0 = wt * 32;
    const int H0 = ht * 12;
    const int D0 = (ds * 130) / DSEGS;          // balanced d split
    const int D1 = ((ds + 1) * 130) / DSEGS;
    const int steps = (D1 - D0) + 4;            // 18 or 19

    const int  w_out = W0 + wl;
    const int  wc    = min(w_out, 129);                 // clamp garbage lanes
    const int  ghW   = min(max(H0 - 2 + r, 0), 129);    // W row (replicated)
    const int  oh    = H0 + r - 2;                      // output row (interior)
    const bool interior = (r >= 2) && (r < 14);
    const bool valid    = interior && (oh < N) && (w_out < N);

    // h-dim precompute (thread-invariant)
    const int   ih_c = min(max(ghW - 1, 0), 127);
    const int   ih_m = min(max(ghW - 3, 0), 127);
    const int   ih_p = min(ghW + 1, 127);
    const float fhm  = (ghW >= 1)   ? 1.0f : 0.0f;
    const float fhp  = (ghW <= 128) ? 1.0f : 0.0f;
    const int   dhm  = (ih_m - ih_c) * XN;
    const int   dhp  = (ih_p - ih_c) * XN;

    // w-dim per-tap precompute (thread-invariant)
    int   oc[5], o4[5], o5[5];
    float fwm[5], fwp[5];
    #pragma unroll
    for (int j = 0; j < 5; ++j) {
        const int cw = min(max(wc + j - 2, 0), 129);
        oc[j] = ih_c * XN + min(max(cw - 1, 0), 127);
        o4[j] = ih_c * XN + min(max(cw - 3, 0), 127);
        o5[j] = ih_c * XN + min(cw + 1, 127);
        fwm[j] = (cw >= 1)   ? 1.0f : 0.0f;
        fwp[j] = (cw <= 128) ? 1.0f : 0.0f;
    }

    __shared__ f32x4 Wlds[2][3][16][32];   // double-buffered plane, 48 KB
    __shared__ float red[512];

    f32x4 ring[5][3];                   // 5-deep d ring, 12 ch as 3x f32x4
    float lsum   = 0.0f;
    int   voxoff = D0 * NN + oh * N + w_out;   // element offset of next output

    // cold-plane (Y1 = d+) prefetch state
    float PF[5];
    float fdpP;

#define PRE(IT) do {                                                          \
    const int bdn = D0 - 2 + (IT);                                            \
    const int dcn = min(max(bdn, 0), 129);                                    \
    const float* ppn = x + (size_t)(min(dcn + 1, 127)) * XNN;                 \
    fdpP = (dcn <= 128) ? 1.0f : 0.0f;                                        \
    _Pragma("unroll") for (int j = 0; j < 5; ++j) PF[j] = ppn[oc[j]];         \
} while (0)

#define STEP(IT, SLOT, DOUT) do {                                             \
    const int it_ = (IT);                                                     \
    const int bd = D0 - 2 + it_;                                              \
    const int dc = min(max(bd, 0), 129);                                      \
    const float* pc = x + (size_t)(min(max(dc - 1, 0), 127)) * XNN;           \
    const float* pm = x + (size_t)(min(max(dc - 3, 0), 127)) * XNN;           \
    const float fdm = (dc >= 1)   ? 1.0f : 0.0f;                              \
    /* consume prefetched cold plane (loaded one step ago) */                 \
    const float fdp_ = fdpP;                                                  \
    float y1v[5];                                                             \
    _Pragma("unroll") for (int j = 0; j < 5; ++j) y1v[j] = PF[j] * fdp_;      \
    PRE(it_ + 1);                       /* issue next cold loads early */     \
    float Wa[12];                                                             \
    _Pragma("unroll") for (int z = 0; z < 12; ++z) Wa[z] = 0.0f;              \
    _Pragma("unroll") for (int j = 0; j < 5; ++j) {                           \
        const float y0 = pm[oc[j]]       * fdm;                               \
        const float y1 = y1v[j];                                              \
        const float y2 = pc[oc[j] + dhm] * fhm;                               \
        const float y3 = pc[oc[j] + dhp] * fhp;                               \
        const float y4 = pc[o4[j]]       * fwm[j];                            \
        const float y5 = pc[o5[j]]       * fwp[j];                            \
        float t;                                                              \
        t = y4 - y0; Wa[0]  += t * t;  t = y2 - y0; Wa[1]  += t * t;          \
        t = y2 - y4; Wa[2]  += t * t;  t = y5 - y0; Wa[3]  += t * t;          \
        t = y5 - y2; Wa[4]  += t * t;  t = y1 - y4; Wa[5]  += t * t;          \
        t = y1 - y2; Wa[6]  += t * t;  t = y1 - y5; Wa[7]  += t * t;          \
        t = y3 - y0; Wa[8]  += t * t;  t = y3 - y4; Wa[9]  += t * t;          \
        t = y3 - y5; Wa[10] += t * t;  t = y3 - y1; Wa[11] += t * t;          \
    }                                                                         \
    const int pb = it_ & 1;                                                   \
    Wlds[pb][0][r][wl] = (f32x4){Wa[0], Wa[1], Wa[2],  Wa[3]};                \
    Wlds[pb][1][r][wl] = (f32x4){Wa[4], Wa[5], Wa[6],  Wa[7]};                \
    Wlds[pb][2][r][wl] = (f32x4){Wa[8], Wa[9], Wa[10], Wa[11]};               \
    /* raw barrier: drain LDS writes only; global loads/stores stay live.  */ \
    /* "memory" clobber orders all compiler-generated LDS ops around it.   */ \
    asm volatile("s_waitcnt lgkmcnt(0)" ::: "memory");                        \
    __builtin_amdgcn_s_barrier();                                             \
    if (interior) {                                                           \
        _Pragma("unroll") for (int g = 0; g < 3; ++g) {                       \
            f32x4 a = Wlds[pb][g][r - 2][wl];                                 \
            a += Wlds[pb][g][r - 1][wl];                                      \
            a += Wlds[pb][g][r    ][wl];                                      \
            a += Wlds[pb][g][r + 1][wl];                                      \
            a += Wlds[pb][g][r + 2][wl];                                      \
            ring[SLOT][g] = a;                                                \
        }                                                                     \
        if (DOUT) {                                                           \
            f32x4 sg[3];                                                      \
            _Pragma("unroll") for (int g = 0; g < 3; ++g) {                   \
                f32x4 a = ring[0][g];                                         \
                a += ring[1][g]; a += ring[2][g];                             \
                a += ring[3][g]; a += ring[4][g];                             \
                sg[g] = a * (1.0f / 125.0f);                                  \
            }                                                                 \
            float sv[12];                                                     \
            _Pragma("unroll") for (int g = 0; g < 3; ++g) {                   \
                sv[4*g+0] = sg[g].x; sv[4*g+1] = sg[g].y;                     \
                sv[4*g+2] = sg[g].z; sv[4*g+3] = sg[g].w;                     \
            }                                                                 \
            float mn = sv[0], tt = sv[0];                                     \
            _Pragma("unroll") for (int z = 1; z < 12; ++z) {                  \
                mn = fminf(mn, sv[z]); tt += sv[z];                           \
            }                                                                 \
            if (valid) {                                                      \
                _Pragma("unroll") for (int z = 0; z < 12; ++z)                \
                    Cout[(size_t)z * NNN + (unsigned)voxoff] = sv[z] - mn;    \
                lsum += tt * (1.0f / 12.0f) - mn;     /* mind_var */          \
                voxoff += NN;                                                 \
            }                                                                 \
        }                                                                     \
    }                                                                         \
} while (0)

    PRE(0);
    // warmup: fill ring slots 0..3 (box planes D0-2 .. D0+1, clamped)
    STEP(0, 0, false);
    STEP(1, 1, false);
    STEP(2, 2, false);
    STEP(3, 3, false);

    // main: its 4..steps-1; base ≡ 4 (mod 5) keeps ring slots compile-time
    for (int base = 4; base < steps; base += 5) {
        STEP(base + 0, 4, true);
        if (base + 1 < steps) STEP(base + 1, 0, true);
        if (base + 2 < steps) STEP(base + 2, 1, true);
        if (base + 3 < steps) STEP(base + 3, 2, true);
        if (base + 4 < steps) STEP(base + 4, 3, true);
    }
#undef STEP
#undef PRE

    // block reduction of mind_var partial sum
    red[tid] = lsum;
    __syncthreads();
    for (int st = 256; st > 0; st >>= 1) {
        if (tid < st) red[tid] += red[tid + st];
        __syncthreads();
    }
    if (tid == 0) atomicAdd(acc, (double)red[0]);
}

// zero the accumulator
__global__ void k_zero(double* acc) {
    if (blockIdx.x == 0 && threadIdx.x == 0) *acc = 0.0;
}

// K3: in-place epilogue on d_out, float4-vectorized, fast exp.
// mvar = mean_ch(mind), clip to [1e-3,1e3]*mean, exp.
__global__ __launch_bounds__(256) void k_exp(float* __restrict__ io,
                                             const double* __restrict__ acc) {
    int q = blockIdx.x * 256 + threadIdx.x;      // float4 index
    if (q >= NQ4) return;
    const float mv_mean = (float)(*acc * (1.0 / (double)NNN));
    const float lo = mv_mean * 0.001f, hi = mv_mean * 1000.0f;

    f32x4 v[NCH];
    f32x4 tot = (f32x4){0.0f, 0.0f, 0.0f, 0.0f};
    #pragma unroll
    for (int o = 0; o < NCH; ++o) {
        v[o] = *((const f32x4*)io + (size_t)o * NQ4 + q);
        tot += v[o];
    }
    f32x4 inv;
    #pragma unroll
    for (int k = 0; k < 4; ++k) {
        float mvar = tot[k] * (1.0f / 12.0f);
        mvar = fminf(fmaxf(mvar, lo), hi);
        inv[k] = 1.0f / mvar;
    }
    #pragma unroll
    for (int o = 0; o < NCH; ++o) {
        f32x4 rr;
        #pragma unroll
        for (int k = 0; k < 4; ++k)
            rr[k] = __expf(-v[o][k] * inv[k]);
        *((f32x4*)io + (size_t)o * NQ4 + q) = rr;
    }
}

extern "C" void kernel_launch(void* const* d_in, const int* in_sizes, int n_in,
                              void* d_out, int out_size, void* d_ws, size_t ws_size,
                              hipStream_t stream) {
    const float* x = (const float*)d_in[0];
    float* out = (float*)d_out;                 // [12,130,130,130] f32
    double* acc = (double*)d_ws;

    k_zero <<<1, 64, 0, stream>>>(acc);
    k_fused<<<WT * HT * DSEGS, 512, 0, stream>>>(x, out, acc);   // 495 blocks
    k_exp  <<<(NQ4 + 255) / 256, 256, 0, stream>>>(out, acc);    // 2146 blocks
}

// Round 5
// 188.980 us; speedup vs baseline: 1.9516x; 1.1235x over previous
//
#include <hip/hip_runtime.h>
#include <math.h>

// Problem constants
#define N    130
#define NN   (130*130)       // 16900
#define NNN  (130*130*130)   // 2197000
#define NQ4  (NNN/4)         // 549250
#define NCH  12
#define XN   128
#define XNN  (XN*XN)

// Fused-kernel tiling
#define WT   5               // w tiles (32 lanes each, last partially valid)
#define HT   11              // h tiles (12 output rows each, 16 W rows computed)
#define DSEGS 9              // d segments, balanced: grid = 5*11*9 = 495 <= 512
                             // co-resident blocks (2/CU at <=128 VGPR)

typedef float f32x4 __attribute__((ext_vector_type(4)));

// ---------------------------------------------------------------------------
// Fused kernel: conv-diff^2 + 5x5x5 replicated box + channel min/mean + EXP.
//
// 12 channels = 12 orthogonal pairs of 6 shared neighbour values
//   Y0=d-, Y1=d+, Y2=h-, Y3=h+, Y4=w-, Y5=w+   (dilation-2 face neighbours)
// Per-dim addressing in box coords c in [0,129] (verified vs SH tables):
//   class  1 (center): ix = clamp(c-1,0,127), always valid
//   class -1:          ix = clamp(c-3,0,127), masked iff c==0
//   class  3:          ix = clamp(c+1,0,127), masked iff c==129
// Pairs: 0:(Y4,Y0) 1:(Y2,Y0) 2:(Y2,Y4) 3:(Y5,Y0) 4:(Y5,Y2) 5:(Y1,Y4)
//        6:(Y1,Y2) 7:(Y1,Y5) 8:(Y3,Y0) 9:(Y3,Y4) 10:(Y3,Y5) 11:(Y3,Y1)
//
// R5 change vs R4: the 211-MB k_exp round trip is ELIMINATED. k_fused now
// writes out = __expf(-mind * 1/max(mvar,1e-20)) directly (unclipped) and
// stores the per-voxel mvar plane (8.8 MB) to workspace. A tiny second pass
// (k_fix) applies the global-mean clip algebraically where it binds:
//   out_correct = out ^ (mvar_raw / mvar_clipped)
// which is a no-op (exponent 1) for every voxel where the clip is inactive.
// ---------------------------------------------------------------------------
__global__ __launch_bounds__(512) void k_fused(const float* __restrict__ x,
                                               float* __restrict__ Cout,
                                               float* __restrict__ MV,
                                               double* __restrict__ acc) {
    const int tid = threadIdx.x;
    const int wl  = tid & 31;
    const int r   = tid >> 5;

    const int b    = blockIdx.x;
    const int wt   = b % WT;
    const int rest = b / WT;
    const int ht   = rest % HT;
    const int ds   = rest / HT;

    const int W0 = wt * 32;
    const int H0 = ht * 12;
    const int D0 = (ds * 130) / DSEGS;          // balanced d split
    const int D1 = ((ds + 1) * 130) / DSEGS;
    const int steps = (D1 - D0) + 4;            // 18 or 19

    const int  w_out = W0 + wl;
    const int  wc    = min(w_out, 129);                 // clamp garbage lanes
    const int  ghW   = min(max(H0 - 2 + r, 0), 129);    // W row (replicated)
    const int  oh    = H0 + r - 2;                      // output row (interior)
    const bool interior = (r >= 2) && (r < 14);
    const bool valid    = interior && (oh < N) && (w_out < N);

    // h-dim precompute (thread-invariant)
    const int   ih_c = min(max(ghW - 1, 0), 127);
    const int   ih_m = min(max(ghW - 3, 0), 127);
    const int   ih_p = min(ghW + 1, 127);
    const float fhm  = (ghW >= 1)   ? 1.0f : 0.0f;
    const float fhp  = (ghW <= 128) ? 1.0f : 0.0f;
    const int   dhm  = (ih_m - ih_c) * XN;
    const int   dhp  = (ih_p - ih_c) * XN;

    // w-dim per-tap precompute (thread-invariant)
    int   oc[5], o4[5], o5[5];
    float fwm[5], fwp[5];
    #pragma unroll
    for (int j = 0; j < 5; ++j) {
        const int cw = min(max(wc + j - 2, 0), 129);
        oc[j] = ih_c * XN + min(max(cw - 1, 0), 127);
        o4[j] = ih_c * XN + min(max(cw - 3, 0), 127);
        o5[j] = ih_c * XN + min(cw + 1, 127);
        fwm[j] = (cw >= 1)   ? 1.0f : 0.0f;
        fwp[j] = (cw <= 128) ? 1.0f : 0.0f;
    }

    __shared__ f32x4 Wlds[2][3][16][32];   // double-buffered plane, 48 KB
    __shared__ float red[512];

    f32x4 ring[5][3];                   // 5-deep d ring, 12 ch as 3x f32x4
    float lsum   = 0.0f;
    int   voxoff = D0 * NN + oh * N + w_out;   // element offset of next output

    // cold-plane (Y1 = d+) prefetch state
    float PF[5];
    float fdpP;

#define PRE(IT) do {                                                          \
    const int bdn = D0 - 2 + (IT);                                            \
    const int dcn = min(max(bdn, 0), 129);                                    \
    const float* ppn = x + (size_t)(min(dcn + 1, 127)) * XNN;                 \
    fdpP = (dcn <= 128) ? 1.0f : 0.0f;                                        \
    _Pragma("unroll") for (int j = 0; j < 5; ++j) PF[j] = ppn[oc[j]];         \
} while (0)

#define STEP(IT, SLOT, DOUT) do {                                             \
    const int it_ = (IT);                                                     \
    const int bd = D0 - 2 + it_;                                              \
    const int dc = min(max(bd, 0), 129);                                      \
    const float* pc = x + (size_t)(min(max(dc - 1, 0), 127)) * XNN;           \
    const float* pm = x + (size_t)(min(max(dc - 3, 0), 127)) * XNN;           \
    const float fdm = (dc >= 1)   ? 1.0f : 0.0f;                              \
    /* consume prefetched cold plane (loaded one step ago) */                 \
    const float fdp_ = fdpP;                                                  \
    float y1v[5];                                                             \
    _Pragma("unroll") for (int j = 0; j < 5; ++j) y1v[j] = PF[j] * fdp_;      \
    PRE(it_ + 1);                       /* issue next cold loads early */     \
    float Wa[12];                                                             \
    _Pragma("unroll") for (int z = 0; z < 12; ++z) Wa[z] = 0.0f;              \
    _Pragma("unroll") for (int j = 0; j < 5; ++j) {                           \
        const float y0 = pm[oc[j]]       * fdm;                               \
        const float y1 = y1v[j];                                              \
        const float y2 = pc[oc[j] + dhm] * fhm;                               \
        const float y3 = pc[oc[j] + dhp] * fhp;                               \
        const float y4 = pc[o4[j]]       * fwm[j];                            \
        const float y5 = pc[o5[j]]       * fwp[j];                            \
        float t;                                                              \
        t = y4 - y0; Wa[0]  += t * t;  t = y2 - y0; Wa[1]  += t * t;          \
        t = y2 - y4; Wa[2]  += t * t;  t = y5 - y0; Wa[3]  += t * t;          \
        t = y5 - y2; Wa[4]  += t * t;  t = y1 - y4; Wa[5]  += t * t;          \
        t = y1 - y2; Wa[6]  += t * t;  t = y1 - y5; Wa[7]  += t * t;          \
        t = y3 - y0; Wa[8]  += t * t;  t = y3 - y4; Wa[9]  += t * t;          \
        t = y3 - y5; Wa[10] += t * t;  t = y3 - y1; Wa[11] += t * t;          \
    }                                                                         \
    const int pb = it_ & 1;                                                   \
    Wlds[pb][0][r][wl] = (f32x4){Wa[0], Wa[1], Wa[2],  Wa[3]};                \
    Wlds[pb][1][r][wl] = (f32x4){Wa[4], Wa[5], Wa[6],  Wa[7]};                \
    Wlds[pb][2][r][wl] = (f32x4){Wa[8], Wa[9], Wa[10], Wa[11]};               \
    /* raw barrier: drain LDS writes only; global loads/stores stay live.  */ \
    asm volatile("s_waitcnt lgkmcnt(0)" ::: "memory");                        \
    __builtin_amdgcn_s_barrier();                                             \
    if (interior) {                                                           \
        _Pragma("unroll") for (int g = 0; g < 3; ++g) {                       \
            f32x4 a = Wlds[pb][g][r - 2][wl];                                 \
            a += Wlds[pb][g][r - 1][wl];                                      \
            a += Wlds[pb][g][r    ][wl];                                      \
            a += Wlds[pb][g][r + 1][wl];                                      \
            a += Wlds[pb][g][r + 2][wl];                                      \
            ring[SLOT][g] = a;                                                \
        }                                                                     \
        if (DOUT) {                                                           \
            f32x4 sg[3];                                                      \
            _Pragma("unroll") for (int g = 0; g < 3; ++g) {                   \
                f32x4 a = ring[0][g];                                         \
                a += ring[1][g]; a += ring[2][g];                             \
                a += ring[3][g]; a += ring[4][g];                             \
                sg[g] = a * (1.0f / 125.0f);                                  \
            }                                                                 \
            float sv[12];                                                     \
            _Pragma("unroll") for (int g = 0; g < 3; ++g) {                   \
                sv[4*g+0] = sg[g].x; sv[4*g+1] = sg[g].y;                     \
                sv[4*g+2] = sg[g].z; sv[4*g+3] = sg[g].w;                     \
            }                                                                 \
            float mn = sv[0], tt = sv[0];                                     \
            _Pragma("unroll") for (int z = 1; z < 12; ++z) {                  \
                mn = fminf(mn, sv[z]); tt += sv[z];                           \
            }                                                                 \
            if (valid) {                                                      \
                const float mvar = tt * (1.0f / 12.0f) - mn;                  \
                const float inv  = 1.0f / fmaxf(mvar, 1e-20f);                \
                _Pragma("unroll") for (int z = 0; z < 12; ++z)                \
                    Cout[(size_t)z * NNN + (unsigned)voxoff] =                \
                        __expf(-(sv[z] - mn) * inv);                          \
                MV[(unsigned)voxoff] = mvar;                                  \
                lsum += mvar;                                                 \
                voxoff += NN;                                                 \
            }                                                                 \
        }                                                                     \
    }                                                                         \
} while (0)

    PRE(0);
    // warmup: fill ring slots 0..3 (box planes D0-2 .. D0+1, clamped)
    STEP(0, 0, false);
    STEP(1, 1, false);
    STEP(2, 2, false);
    STEP(3, 3, false);

    // main: its 4..steps-1; base ≡ 4 (mod 5) keeps ring slots compile-time
    for (int base = 4; base < steps; base += 5) {
        STEP(base + 0, 4, true);
        if (base + 1 < steps) STEP(base + 1, 0, true);
        if (base + 2 < steps) STEP(base + 2, 1, true);
        if (base + 3 < steps) STEP(base + 3, 2, true);
        if (base + 4 < steps) STEP(base + 4, 3, true);
    }
#undef STEP
#undef PRE

    // block reduction of mind_var partial sum
    red[tid] = lsum;
    __syncthreads();
    for (int st = 256; st > 0; st >>= 1) {
        if (tid < st) red[tid] += red[tid + st];
        __syncthreads();
    }
    if (tid == 0) atomicAdd(acc, (double)red[0]);
}

// zero the accumulator
__global__ void k_zero(double* acc) {
    if (blockIdx.x == 0 && threadIdx.x == 0) *acc = 0.0;
}

// k_fix: apply the global-mean clip where it binds (rare / usually never).
// Pass 1 wrote out = exp(-mind/max(mvar,1e-20)); the clipped-correct value is
// out^(mvar_used/mvar_clipped). Streams only the 8.8 MB mvar plane.
__global__ __launch_bounds__(256) void k_fix(float* __restrict__ io,
                                             const float* __restrict__ MV,
                                             const double* __restrict__ acc) {
    int q = blockIdx.x * 256 + threadIdx.x;      // float4 index
    if (q >= NQ4) return;
    const float mv_mean = (float)(*acc * (1.0 / (double)NNN));
    const float lo = mv_mean * 0.001f, hi = mv_mean * 1000.0f;
    const f32x4 mv = *((const f32x4*)MV + q);
    #pragma unroll
    for (int k = 0; k < 4; ++k) {
        const float used = fmaxf(mv[k], 1e-20f);
        const float cl   = fminf(fmaxf(mv[k], lo), hi);
        const float e    = used / cl;
        if (fabsf(e - 1.0f) > 1e-6f) {
            const size_t vox = (size_t)q * 4 + k;
            #pragma unroll
            for (int o = 0; o < NCH; ++o) {
                const float v = io[(size_t)o * NNN + vox];
                if (v > 0.0f)
                    io[(size_t)o * NNN + vox] = powf(v, e);
            }
        }
    }
}

extern "C" void kernel_launch(void* const* d_in, const int* in_sizes, int n_in,
                              void* d_out, int out_size, void* d_ws, size_t ws_size,
                              hipStream_t stream) {
    const float* x = (const float*)d_in[0];
    float* out = (float*)d_out;                 // [12,130,130,130] f32
    float* MV  = (float*)d_ws;                  // mvar plane, NNN floats
    double* acc = (double*)((char*)d_ws + (size_t)NNN * sizeof(float));

    k_zero <<<1, 64, 0, stream>>>(acc);
    k_fused<<<WT * HT * DSEGS, 512, 0, stream>>>(x, out, MV, acc); // 495 blocks
    k_fix  <<<(NQ4 + 255) / 256, 256, 0, stream>>>(out, MV, acc);  // 2146 blocks
}

// Round 6
// 187.300 us; speedup vs baseline: 1.9691x; 1.0090x over previous
//
#include <hip/hip_runtime.h>
#include <math.h>

// Problem constants
#define N    130
#define NN   (130*130)       // 16900
#define NNN  (130*130*130)   // 2197000
#define NQ4  (NNN/4)         // 549250
#define NCH  12
#define XN   128
#define XNN  (XN*XN)

// Fused-kernel tiling (R6: small independent barrier groups)
#define WT   9               // w tiles of 16 lanes (144 >= 130)
#define HT   11              // h tiles (12 output rows each, 16 W rows computed)
#define DSEGS 13             // d strips of exactly 10 output planes
#define STEPS 14             // 10 + 4 warmup
// grid = 9*11*13 = 1287 blocks of 256 thr -> ~5 co-resident blocks/CU:
// many small out-of-phase barrier groups keep the LDS pipe fed instead of
// one block-wide post-barrier read burst sitting on the critical path.

typedef float f32x4 __attribute__((ext_vector_type(4)));

// ---------------------------------------------------------------------------
// Fused kernel: conv-diff^2 + 5x5x5 replicated box + channel min/mean + exp.
//
// 12 channels = 12 orthogonal pairs of 6 shared neighbour values
//   Y0=d-, Y1=d+, Y2=h-, Y3=h+, Y4=w-, Y5=w+   (dilation-2 face neighbours)
// Per-dim addressing in box coords c in [0,129] (verified vs SH tables):
//   class  1 (center): ix = clamp(c-1,0,127), always valid
//   class -1:          ix = clamp(c-3,0,127), masked iff c==0
//   class  3:          ix = clamp(c+1,0,127), masked iff c==129
// Pairs: 0:(Y4,Y0) 1:(Y2,Y0) 2:(Y2,Y4) 3:(Y5,Y0) 4:(Y5,Y2) 5:(Y1,Y4)
//        6:(Y1,Y2) 7:(Y1,Y5) 8:(Y3,Y0) 9:(Y3,Y4) 10:(Y3,Y5) 11:(Y3,Y1)
//
// Block = 256 threads (16 w-lanes x 16 h-rows), walks a 10-plane d strip.
// Per step: W-box diff^2 (all 12 ch), LDS plane exchange (dbuf, one raw
// lgkmcnt-barrier), 5-tap h-sum, 5-deep d register ring, emit
// out = exp(-mind/mvar_raw) + the mvar plane for the clip fix-up pass.
// ---------------------------------------------------------------------------
__global__ __launch_bounds__(256) void k_fused(const float* __restrict__ x,
                                               float* __restrict__ Cout,
                                               float* __restrict__ MV,
                                               double* __restrict__ acc) {
    const int tid = threadIdx.x;
    const int wl  = tid & 15;
    const int r   = tid >> 4;

    const int b    = blockIdx.x;
    const int wt   = b % WT;
    const int rest = b / WT;
    const int ht   = rest % HT;
    const int ds   = rest / HT;

    const int W0 = wt * 16;
    const int H0 = ht * 12;
    const int D0 = ds * 10;             // exact: 130/13 = 10

    const int  w_out = W0 + wl;
    const int  wc    = min(w_out, 129);                 // clamp garbage lanes
    const int  ghW   = min(max(H0 - 2 + r, 0), 129);    // W row (replicated)
    const int  oh    = H0 + r - 2;                      // output row (interior)
    const bool interior = (r >= 2) && (r < 14);
    const bool valid    = interior && (oh < N) && (w_out < N);

    // h-dim precompute (thread-invariant)
    const int   ih_c = min(max(ghW - 1, 0), 127);
    const int   ih_m = min(max(ghW - 3, 0), 127);
    const int   ih_p = min(ghW + 1, 127);
    const float fhm  = (ghW >= 1)   ? 1.0f : 0.0f;
    const float fhp  = (ghW <= 128) ? 1.0f : 0.0f;
    const int   dhm  = (ih_m - ih_c) * XN;
    const int   dhp  = (ih_p - ih_c) * XN;

    // w-dim per-tap precompute (thread-invariant)
    int   oc[5], o4[5], o5[5];
    float fwm[5], fwp[5];
    #pragma unroll
    for (int j = 0; j < 5; ++j) {
        const int cw = min(max(wc + j - 2, 0), 129);
        oc[j] = ih_c * XN + min(max(cw - 1, 0), 127);
        o4[j] = ih_c * XN + min(max(cw - 3, 0), 127);
        o5[j] = ih_c * XN + min(cw + 1, 127);
        fwm[j] = (cw >= 1)   ? 1.0f : 0.0f;
        fwp[j] = (cw <= 128) ? 1.0f : 0.0f;
    }

    __shared__ f32x4 Wlds[2][3][16][16];   // double-buffered plane, 24 KB
    __shared__ float red[256];

    f32x4 ring[5][3];                   // 5-deep d ring, 12 ch as 3x f32x4
    float lsum   = 0.0f;
    int   voxoff = D0 * NN + oh * N + w_out;   // element offset of next output

    // cold-plane (Y1 = d+) prefetch state
    float PF[5];
    float fdpP;

#define PRE(IT) do {                                                          \
    const int bdn = D0 - 2 + (IT);                                            \
    const int dcn = min(max(bdn, 0), 129);                                    \
    const float* ppn = x + (size_t)(min(dcn + 1, 127)) * XNN;                 \
    fdpP = (dcn <= 128) ? 1.0f : 0.0f;                                        \
    _Pragma("unroll") for (int j = 0; j < 5; ++j) PF[j] = ppn[oc[j]];         \
} while (0)

#define STEP(IT, SLOT, DOUT) do {                                             \
    const int it_ = (IT);                                                     \
    const int bd = D0 - 2 + it_;                                              \
    const int dc = min(max(bd, 0), 129);                                      \
    const float* pc = x + (size_t)(min(max(dc - 1, 0), 127)) * XNN;           \
    const float* pm = x + (size_t)(min(max(dc - 3, 0), 127)) * XNN;           \
    const float fdm = (dc >= 1)   ? 1.0f : 0.0f;                              \
    /* consume prefetched cold plane (loaded one step ago) */                 \
    const float fdp_ = fdpP;                                                  \
    float y1v[5];                                                             \
    _Pragma("unroll") for (int j = 0; j < 5; ++j) y1v[j] = PF[j] * fdp_;      \
    PRE(it_ + 1);                       /* issue next cold loads early */     \
    float Wa[12];                                                             \
    _Pragma("unroll") for (int z = 0; z < 12; ++z) Wa[z] = 0.0f;              \
    _Pragma("unroll") for (int j = 0; j < 5; ++j) {                           \
        const float y0 = pm[oc[j]]       * fdm;                               \
        const float y1 = y1v[j];                                              \
        const float y2 = pc[oc[j] + dhm] * fhm;                               \
        const float y3 = pc[oc[j] + dhp] * fhp;                               \
        const float y4 = pc[o4[j]]       * fwm[j];                            \
        const float y5 = pc[o5[j]]       * fwp[j];                            \
        float t;                                                              \
        t = y4 - y0; Wa[0]  += t * t;  t = y2 - y0; Wa[1]  += t * t;          \
        t = y2 - y4; Wa[2]  += t * t;  t = y5 - y0; Wa[3]  += t * t;          \
        t = y5 - y2; Wa[4]  += t * t;  t = y1 - y4; Wa[5]  += t * t;          \
        t = y1 - y2; Wa[6]  += t * t;  t = y1 - y5; Wa[7]  += t * t;          \
        t = y3 - y0; Wa[8]  += t * t;  t = y3 - y4; Wa[9]  += t * t;          \
        t = y3 - y5; Wa[10] += t * t;  t = y3 - y1; Wa[11] += t * t;          \
    }                                                                         \
    const int pb = it_ & 1;                                                   \
    Wlds[pb][0][r][wl] = (f32x4){Wa[0], Wa[1], Wa[2],  Wa[3]};                \
    Wlds[pb][1][r][wl] = (f32x4){Wa[4], Wa[5], Wa[6],  Wa[7]};                \
    Wlds[pb][2][r][wl] = (f32x4){Wa[8], Wa[9], Wa[10], Wa[11]};               \
    /* raw barrier: drain LDS writes only; global loads/stores stay live.  */ \
    asm volatile("s_waitcnt lgkmcnt(0)" ::: "memory");                        \
    __builtin_amdgcn_s_barrier();                                             \
    if (interior) {                                                           \
        _Pragma("unroll") for (int g = 0; g < 3; ++g) {                       \
            f32x4 a = Wlds[pb][g][r - 2][wl];                                 \
            a += Wlds[pb][g][r - 1][wl];                                      \
            a += Wlds[pb][g][r    ][wl];                                      \
            a += Wlds[pb][g][r + 1][wl];                                      \
            a += Wlds[pb][g][r + 2][wl];                                      \
            ring[SLOT][g] = a;                                                \
        }                                                                     \
        if (DOUT) {                                                           \
            f32x4 sg[3];                                                      \
            _Pragma("unroll") for (int g = 0; g < 3; ++g) {                   \
                f32x4 a = ring[0][g];                                         \
                a += ring[1][g]; a += ring[2][g];                             \
                a += ring[3][g]; a += ring[4][g];                             \
                sg[g] = a * (1.0f / 125.0f);                                  \
            }                                                                 \
            float sv[12];                                                     \
            _Pragma("unroll") for (int g = 0; g < 3; ++g) {                   \
                sv[4*g+0] = sg[g].x; sv[4*g+1] = sg[g].y;                     \
                sv[4*g+2] = sg[g].z; sv[4*g+3] = sg[g].w;                     \
            }                                                                 \
            float mn = sv[0], tt = sv[0];                                     \
            _Pragma("unroll") for (int z = 1; z < 12; ++z) {                  \
                mn = fminf(mn, sv[z]); tt += sv[z];                           \
            }                                                                 \
            if (valid) {                                                      \
                const float mvar = tt * (1.0f / 12.0f) - mn;                  \
                const float inv  = 1.0f / fmaxf(mvar, 1e-20f);                \
                _Pragma("unroll") for (int z = 0; z < 12; ++z)                \
                    Cout[(size_t)z * NNN + (unsigned)voxoff] =                \
                        __expf(-(sv[z] - mn) * inv);                          \
                MV[(unsigned)voxoff] = mvar;                                  \
                lsum += mvar;                                                 \
                voxoff += NN;                                                 \
            }                                                                 \
        }                                                                     \
    }                                                                         \
} while (0)

    PRE(0);
    // warmup: fill ring slots 0..3 (box planes D0-2 .. D0+1, clamped)
    STEP(0, 0, false);
    STEP(1, 1, false);
    STEP(2, 2, false);
    STEP(3, 3, false);

    // main: its 4..13; base ≡ 4 (mod 5) keeps ring slots compile-time
    STEP(4, 4, true);  STEP(5, 0, true);  STEP(6, 1, true);
    STEP(7, 2, true);  STEP(8, 3, true);
    STEP(9, 4, true);  STEP(10, 0, true); STEP(11, 1, true);
    STEP(12, 2, true); STEP(13, 3, true);
#undef STEP
#undef PRE

    // block reduction of mind_var partial sum
    red[tid] = lsum;
    __syncthreads();
    for (int st = 128; st > 0; st >>= 1) {
        if (tid < st) red[tid] += red[tid + st];
        __syncthreads();
    }
    if (tid == 0) atomicAdd(acc, (double)red[0]);
}

// zero the accumulator
__global__ void k_zero(double* acc) {
    if (blockIdx.x == 0 && threadIdx.x == 0) *acc = 0.0;
}

// k_fix: apply the global-mean clip where it binds (rare / usually never).
// Pass 1 wrote out = exp(-mind/max(mvar,1e-20)); the clipped-correct value is
// out^(mvar_used/mvar_clipped). Streams only the 8.8 MB mvar plane.
__global__ __launch_bounds__(256) void k_fix(float* __restrict__ io,
                                             const float* __restrict__ MV,
                                             const double* __restrict__ acc) {
    const float mv_mean = (float)(*acc * (1.0 / (double)NNN));
    const float lo = mv_mean * 0.001f, hi = mv_mean * 1000.0f;
    for (int q = blockIdx.x * 256 + threadIdx.x; q < NQ4;
         q += gridDim.x * 256) {
        const f32x4 mv = *((const f32x4*)MV + q);
        #pragma unroll
        for (int k = 0; k < 4; ++k) {
            const float used = fmaxf(mv[k], 1e-20f);
            const float cl   = fminf(fmaxf(mv[k], lo), hi);
            const float e    = used / cl;
            if (fabsf(e - 1.0f) > 1e-6f) {
                const size_t vox = (size_t)q * 4 + k;
                #pragma unroll
                for (int o = 0; o < NCH; ++o) {
                    const float v = io[(size_t)o * NNN + vox];
                    if (v > 0.0f)
                        io[(size_t)o * NNN + vox] = __powf(v, e);
                }
            }
        }
    }
}

extern "C" void kernel_launch(void* const* d_in, const int* in_sizes, int n_in,
                              void* d_out, int out_size, void* d_ws, size_t ws_size,
                              hipStream_t stream) {
    const float* x = (const float*)d_in[0];
    float* out = (float*)d_out;                 // [12,130,130,130] f32
    float* MV  = (float*)d_ws;                  // mvar plane, NNN floats
    double* acc = (double*)((char*)d_ws + (size_t)NNN * sizeof(float));

    k_zero <<<1, 64, 0, stream>>>(acc);
    k_fused<<<WT * HT * DSEGS, 256, 0, stream>>>(x, out, MV, acc); // 1287 blocks
    k_fix  <<<1024, 256, 0, stream>>>(out, MV, acc);
}

// Round 7
// 184.746 us; speedup vs baseline: 1.9963x; 1.0138x over previous
//
#include <hip/hip_runtime.h>
#include <math.h>

// Problem constants
#define N    130
#define NN   (130*130)       // 16900
#define NNN  (130*130*130)   // 2197000
#define NQ4  (NNN/4)         // 549250
#define NCH  12
#define XN   128
#define XNN  (XN*XN)

// Fused-kernel tiling (R7: 1 voxel-column per thread, DPP w-box)
#define WT   11              // w tiles: 16 lanes -> 12 valid w (2+2 halo)
#define HT   11              // h tiles: 16 rows  -> 12 valid h (2+2 halo)
#define DSEGS 13             // d strips of exactly 10 output planes
#define NWG  (WT*HT*DSEGS)   // 1573 blocks

typedef float f32x4 __attribute__((ext_vector_type(4)));

// DPP lane-shift within 16-lane rows (VALU pipe, no LDS).
// row_shr:k -> lane i reads lane i-k ; row_shl:k -> lane i reads lane i+k.
// bound_ctrl=1: out-of-row sources read 0 (only reaches discarded halo lanes).
template <int CTRL>
__device__ __forceinline__ float dppf(float v) {
    return __int_as_float(__builtin_amdgcn_update_dpp(
        0, __float_as_int(v), CTRL, 0xF, 0xF, true));
}
#define W5(v) ((v) + dppf<0x111>(v) + dppf<0x112>(v) \
                   + dppf<0x101>(v) + dppf<0x102>(v))

// ---------------------------------------------------------------------------
// Fused kernel: conv-diff^2 + 5x5x5 replicated box + channel min/mean + exp.
//
// 12 channels = 12 orthogonal pairs of 6 shared neighbour values
//   Y0=d-, Y1=d+, Y2=h-, Y3=h+, Y4=w-, Y5=w+   (dilation-2 face neighbours)
// Per-dim addressing in box coords c in [0,129] (verified vs SH tables):
//   class  1 (center): ix = clamp(c-1,0,127), always valid
//   class -1:          ix = clamp(c-3,0,127), masked iff c==0
//   class  3:          ix = clamp(c+1,0,127), masked iff c==129
// Pairs: 0:(Y4,Y0) 1:(Y2,Y0) 2:(Y2,Y4) 3:(Y5,Y0) 4:(Y5,Y2) 5:(Y1,Y4)
//        6:(Y1,Y2) 7:(Y1,Y5) 8:(Y3,Y0) 9:(Y3,Y4) 10:(Y3,Y5) 11:(Y3,Y1)
//
// R7 vs R6: the 5-tap w-window is no longer re-loaded per thread (30 loads /
// thread-step -> 6). Each thread computes diff^2 at its OWN column once; the
// 5-tap w-box is 4 DPP-shifted adds per channel. Halo lanes (wl 0,1,14,15)
// carry edge-clamped columns, which reproduces replication-pad w-taps.
// VMEM instruction count (the modeled TA bottleneck) drops 43->19 per
// wave-step. Block = 16 lanes (12 valid w) x 16 rows (12 valid h), 10-plane
// d strip; LDS exchange only for the h-box; 5-deep d register ring.
// ---------------------------------------------------------------------------
__global__ __launch_bounds__(256) void k_fused(const float* __restrict__ x,
                                               float* __restrict__ Cout,
                                               float* __restrict__ MV,
                                               double* __restrict__ acc,
                                               unsigned* __restrict__ gmm) {
    const int tid = threadIdx.x;
    const int wl  = tid & 15;
    const int r   = tid >> 4;

    // bijective XCD-chunk swizzle (nwg = 1573 = 8*196 + 5)
    const int qq  = NWG >> 3, rm = NWG & 7;
    const int xcd = blockIdx.x & 7, idx = blockIdx.x >> 3;
    const int b   = (xcd < rm ? xcd * (qq + 1)
                              : rm * (qq + 1) + (xcd - rm) * qq) + idx;

    const int wt   = b % WT;
    const int rest = b / WT;
    const int ht   = rest % HT;
    const int ds   = rest / HT;

    const int W0 = wt * 12;
    const int H0 = ht * 12;
    const int D0 = ds * 10;

    const int  w_gl = W0 + wl - 2;                      // global w (halo +-2)
    const int  bw   = min(max(w_gl, 0), 129);           // edge-clamped column
    const int  ghW  = min(max(H0 - 2 + r, 0), 129);     // W row (replicated)
    const int  oh   = H0 + r - 2;                       // output row
    const bool interior = (r >= 2) && (r < 14);
    const bool validw   = (wl >= 2) && (wl < 14) && (w_gl < N);
    const bool valid    = interior && (oh < N) && validw;

    // h-dim precompute (thread-invariant)
    const int   ih_c = min(max(ghW - 1, 0), 127);
    const float fhm  = (ghW >= 1)   ? 1.0f : 0.0f;
    const float fhp  = (ghW <= 128) ? 1.0f : 0.0f;
    const int   dhm  = (min(max(ghW - 3, 0), 127) - ih_c) * XN;
    const int   dhp  = (min(ghW + 1, 127)        - ih_c) * XN;

    // w-dim per-thread column offsets (single tap each now)
    const int   col_c = ih_c * XN + min(max(bw - 1, 0), 127);
    const int   col_m = ih_c * XN + min(max(bw - 3, 0), 127);
    const int   col_p = ih_c * XN + min(bw + 1, 127);
    const float fw_m  = (bw >= 1)   ? 1.0f : 0.0f;
    const float fw_p  = (bw <= 128) ? 1.0f : 0.0f;

    __shared__ f32x4 Wlds[2][3][16][16];   // double-buffered plane, 24 KB
    __shared__ float red[256];

    f32x4 ring[5][3];                   // 5-deep d ring, 12 ch as 3x f32x4
    float lsum  = 0.0f;
    float mn_mv = INFINITY, mx_mv = 0.0f;
    int   voxoff = D0 * NN + oh * N + (valid ? w_gl : 0);

    // cold-plane (Y1 = d+) prefetch state
    float PF, fdpP;

#define PRE(IT) do {                                                          \
    const int dcn = min(max(D0 - 2 + (IT), 0), 129);                          \
    PF   = x[(size_t)(min(dcn + 1, 127)) * XNN + col_c];                      \
    fdpP = (dcn <= 128) ? 1.0f : 0.0f;                                        \
} while (0)

#define STEP(IT, SLOT, DOUT) do {                                             \
    const int it_ = (IT);                                                     \
    const int dc  = min(max(D0 - 2 + it_, 0), 129);                           \
    const float* pc = x + (size_t)(min(max(dc - 1, 0), 127)) * XNN;           \
    const float* pm = x + (size_t)(min(max(dc - 3, 0), 127)) * XNN;           \
    const float fdm = (dc >= 1) ? 1.0f : 0.0f;                                \
    const float y1 = PF * fdpP;          /* prefetched cold plane */          \
    PRE(it_ + 1);                        /* issue next cold load early */     \
    const float y0 = pm[col_c]       * fdm;                                   \
    const float y2 = pc[col_c + dhm] * fhm;                                   \
    const float y3 = pc[col_c + dhp] * fhp;                                   \
    const float y4 = pc[col_m]       * fw_m;                                  \
    const float y5 = pc[col_p]       * fw_p;                                  \
    float Wa[12];                                                             \
    { float t;                                                                \
      t = y4 - y0; Wa[0]  = t * t;  t = y2 - y0; Wa[1]  = t * t;              \
      t = y2 - y4; Wa[2]  = t * t;  t = y5 - y0; Wa[3]  = t * t;              \
      t = y5 - y2; Wa[4]  = t * t;  t = y1 - y4; Wa[5]  = t * t;              \
      t = y1 - y2; Wa[6]  = t * t;  t = y1 - y5; Wa[7]  = t * t;              \
      t = y3 - y0; Wa[8]  = t * t;  t = y3 - y4; Wa[9]  = t * t;              \
      t = y3 - y5; Wa[10] = t * t;  t = y3 - y1; Wa[11] = t * t; }            \
    _Pragma("unroll") for (int z = 0; z < 12; ++z) Wa[z] = W5(Wa[z]);         \
    const int pb = it_ & 1;                                                   \
    Wlds[pb][0][r][wl] = (f32x4){Wa[0], Wa[1], Wa[2],  Wa[3]};                \
    Wlds[pb][1][r][wl] = (f32x4){Wa[4], Wa[5], Wa[6],  Wa[7]};                \
    Wlds[pb][2][r][wl] = (f32x4){Wa[8], Wa[9], Wa[10], Wa[11]};               \
    /* raw barrier: drain LDS writes only; global loads/stores stay live */   \
    asm volatile("s_waitcnt lgkmcnt(0)" ::: "memory");                        \
    __builtin_amdgcn_s_barrier();                                             \
    if (interior) {                                                           \
        _Pragma("unroll") for (int g = 0; g < 3; ++g) {                       \
            f32x4 a = Wlds[pb][g][r - 2][wl];                                 \
            a += Wlds[pb][g][r - 1][wl];                                      \
            a += Wlds[pb][g][r    ][wl];                                      \
            a += Wlds[pb][g][r + 1][wl];                                      \
            a += Wlds[pb][g][r + 2][wl];                                      \
            ring[SLOT][g] = a;                                                \
        }                                                                     \
        if (DOUT) {                                                           \
            f32x4 sg[3];                                                      \
            _Pragma("unroll") for (int g = 0; g < 3; ++g) {                   \
                f32x4 a = ring[0][g];                                         \
                a += ring[1][g]; a += ring[2][g];                             \
                a += ring[3][g]; a += ring[4][g];                             \
                sg[g] = a * (1.0f / 125.0f);                                  \
            }                                                                 \
            float sv[12];                                                     \
            _Pragma("unroll") for (int g = 0; g < 3; ++g) {                   \
                sv[4*g+0] = sg[g].x; sv[4*g+1] = sg[g].y;                     \
                sv[4*g+2] = sg[g].z; sv[4*g+3] = sg[g].w;                     \
            }                                                                 \
            float mn = sv[0], tt = sv[0];                                     \
            _Pragma("unroll") for (int z = 1; z < 12; ++z) {                  \
                mn = fminf(mn, sv[z]); tt += sv[z];                           \
            }                                                                 \
            if (valid) {                                                      \
                const float mvar = tt * (1.0f / 12.0f) - mn;                  \
                const float inv  = 1.0f / fmaxf(mvar, 1e-20f);                \
                _Pragma("unroll") for (int z = 0; z < 12; ++z)                \
                    Cout[(size_t)z * NNN + (unsigned)voxoff] =                \
                        __expf(-(sv[z] - mn) * inv);                          \
                MV[(unsigned)voxoff] = mvar;                                  \
                lsum += mvar;                                                 \
                mn_mv = fminf(mn_mv, mvar);                                   \
                mx_mv = fmaxf(mx_mv, mvar);                                   \
                voxoff += NN;                                                 \
            }                                                                 \
        }                                                                     \
    }                                                                         \
} while (0)

    PRE(0);
    // warmup: fill ring slots 0..3 (box planes D0-2 .. D0+1, clamped)
    STEP(0, 0, false);
    STEP(1, 1, false);
    STEP(2, 2, false);
    STEP(3, 3, false);
    // main: 10 output planes; slots stay compile-time
    STEP(4, 4, true);  STEP(5, 0, true);  STEP(6, 1, true);
    STEP(7, 2, true);  STEP(8, 3, true);
    STEP(9, 4, true);  STEP(10, 0, true); STEP(11, 1, true);
    STEP(12, 2, true); STEP(13, 3, true);
#undef STEP
#undef PRE

    // block reductions: sum, min, max of mvar
    red[tid] = lsum;
    __syncthreads();
    for (int st = 128; st > 0; st >>= 1) {
        if (tid < st) red[tid] += red[tid + st];
        __syncthreads();
    }
    if (tid == 0) atomicAdd(acc, (double)red[0]);
    __syncthreads();
    red[tid] = mn_mv;
    __syncthreads();
    for (int st = 128; st > 0; st >>= 1) {
        if (tid < st) red[tid] = fminf(red[tid], red[tid + st]);
        __syncthreads();
    }
    if (tid == 0) atomicMin(&gmm[0], __float_as_uint(red[0]));
    __syncthreads();
    red[tid] = mx_mv;
    __syncthreads();
    for (int st = 128; st > 0; st >>= 1) {
        if (tid < st) red[tid] = fmaxf(red[tid], red[tid + st]);
        __syncthreads();
    }
    if (tid == 0) atomicMax(&gmm[1], __float_as_uint(red[0]));
}

// zero/init the reduction cells
__global__ void k_zero(double* acc, unsigned* gmm) {
    if (blockIdx.x == 0 && threadIdx.x == 0) {
        *acc = 0.0;
        gmm[0] = 0xFFFFFFFFu;   // running min of float bits (mvar >= 0)
        gmm[1] = 0u;            // running max
    }
}

// k_fix: apply the global-mean clip only where it binds. If the clip binds
// nowhere (gmin >= lo && gmax <= hi), the whole grid exits after 4 loads.
// Pass 1 wrote out = exp(-mind/max(mvar,1e-20)); clipped-correct value is
// out^(mvar_used/mvar_clipped).
__global__ __launch_bounds__(256) void k_fix(float* __restrict__ io,
                                             const float* __restrict__ MV,
                                             const double* __restrict__ acc,
                                             const unsigned* __restrict__ gmm) {
    const float mv_mean = (float)(*acc * (1.0 / (double)NNN));
    const float lo = mv_mean * 0.001f, hi = mv_mean * 1000.0f;
    const float gmin = __uint_as_float(gmm[0]);
    const float gmax = __uint_as_float(gmm[1]);
    if (gmin >= lo && gmax <= hi) return;          // uniform early-out
    for (int q = blockIdx.x * 256 + threadIdx.x; q < NQ4;
         q += gridDim.x * 256) {
        const f32x4 mv = *((const f32x4*)MV + q);
        #pragma unroll
        for (int k = 0; k < 4; ++k) {
            const float used = fmaxf(mv[k], 1e-20f);
            const float cl   = fminf(fmaxf(mv[k], lo), hi);
            const float e    = used / cl;
            if (fabsf(e - 1.0f) > 1e-6f) {
                const size_t vox = (size_t)q * 4 + k;
                #pragma unroll
                for (int o = 0; o < NCH; ++o) {
                    const float v = io[(size_t)o * NNN + vox];
                    if (v > 0.0f)
                        io[(size_t)o * NNN + vox] = __powf(v, e);
                }
            }
        }
    }
}

extern "C" void kernel_launch(void* const* d_in, const int* in_sizes, int n_in,
                              void* d_out, int out_size, void* d_ws, size_t ws_size,
                              hipStream_t stream) {
    const float* x = (const float*)d_in[0];
    float* out = (float*)d_out;                 // [12,130,130,130] f32
    float* MV  = (float*)d_ws;                  // mvar plane, NNN floats
    double*  acc = (double*)((char*)d_ws + (size_t)NNN * sizeof(float));
    unsigned* gmm = (unsigned*)((char*)d_ws + (size_t)NNN * sizeof(float) + 8);

    k_zero <<<1, 64, 0, stream>>>(acc, gmm);
    k_fused<<<NWG, 256, 0, stream>>>(x, out, MV, acc, gmm);  // 1573 blocks
    k_fix  <<<1024, 256, 0, stream>>>(out, MV, acc, gmm);
}